// Round 4
// baseline (197.893 us; speedup 1.0000x reference)
//
#include <hip/hip_runtime.h>
#include <hip/hip_bf16.h>
#include <math.h>

#define B_DIM 8
#define C_DIM 32
#define N_DIM 4096
#define KSPLIT 4
#define KSL (N_DIM / KSPLIT)   // 1024 K per block

typedef short bf16x8 __attribute__((ext_vector_type(8)));   // 8 bf16 = 4 VGPRs
typedef float f32x4 __attribute__((ext_vector_type(4)));
typedef unsigned int uint4v __attribute__((ext_vector_type(4)));

__device__ __forceinline__ ushort f2bf_rne(float f) {
  unsigned u = __float_as_uint(f);
  u += 0x7FFF + ((u >> 16) & 1);
  return (ushort)(u >> 16);
}

// Kernel 1: cadj[b,n] = mean_c x[b,c,n]; feab[b,c,n] = bf16(x[b,c,n])
__global__ __launch_bounds__(256) void prep_kernel(const float* __restrict__ x,
                                                   float* __restrict__ cadj,
                                                   ushort* __restrict__ feab) {
  int idx = blockIdx.x * 256 + threadIdx.x;   // 0 .. B*N-1
  int b = idx >> 12;
  int n = idx & (N_DIM - 1);
  const float* p = x + (size_t)b * C_DIM * N_DIM + n;
  ushort* q = feab + (size_t)b * C_DIM * N_DIM + n;
  float s = 0.f;
#pragma unroll
  for (int c = 0; c < C_DIM; ++c) {
    float v = p[(size_t)c * N_DIM];
    s += v;
    q[(size_t)c * N_DIM] = f2bf_rne(v);
  }
  cadj[idx] = s * (1.0f / C_DIM);
}

// Kernel 2: block = 8 waves; wave w = batch w. Block covers (16 cols) x (K-slice 1024),
// ALL batches -> the 8 waves read IDENTICAL adj addresses (L1-shared, adj read once from HBM).
// No LDS, no barriers. Partials to ws, reduced by epilogue kernel.
__global__ __launch_bounds__(512, 8) void gcn_stage1(
    const ushort* __restrict__ feab, const float* __restrict__ adj,
    const float* __restrict__ cadj, float* __restrict__ part) {
  const int tid = threadIdx.x;
  const int lane = tid & 63;
  const int b = tid >> 6;           // wave id = batch
  const int quad = lane >> 4;
  const int l15 = lane & 15;
  const int colgrp = blockIdx.x;    // 0..255
  const int ks = blockIdx.y;        // 0..KSPLIT-1
  const int col = colgrp * 16 + l15;
  const int ksbase = ks * KSL;

  const float cm = cadj[b * N_DIM + col];
  const ushort* fb = feab + (size_t)b * C_DIM * N_DIM + ksbase;
  const float* ck = cadj + b * N_DIM + ksbase;

  f32x4 acc0 = {0.f, 0.f, 0.f, 0.f};   // channels 0-15
  f32x4 acc1 = {0.f, 0.f, 0.f, 0.f};   // channels 16-31

#pragma unroll 2
  for (int ch = 0; ch < KSL / 32; ++ch) {
    const int kb = ch * 32 + quad * 8;   // k offset within slice

    // adj fragment — same addresses for all 8 waves of the block (L1 reuse)
    float adjv[8];
#pragma unroll
    for (int j = 0; j < 8; ++j)
      adjv[j] = adj[(size_t)(ksbase + kb + j) * N_DIM + col];

    float ckv[8];
    *(f32x4*)&ckv[0] = *(const f32x4*)(ck + kb);
    *(f32x4*)&ckv[4] = *(const f32x4*)(ck + kb + 4);

    const bf16x8 fa0 = *(const bf16x8*)(fb + l15 * N_DIM + kb);
    const bf16x8 fa1 = *(const bf16x8*)(fb + (16 + l15) * N_DIM + kb);

    // w = 2*adj / (1 + exp2(1.4427*|d|));  even in d => symmetrization is identity
    uint4v wfu;
#pragma unroll
    for (int p = 0; p < 4; ++p) {
      float d0 = ckv[2 * p] - cm;
      float e0 = __builtin_amdgcn_exp2f(fabsf(d0) * 1.44269504f);
      float w0 = (2.0f * adjv[2 * p]) * __builtin_amdgcn_rcpf(1.0f + e0);
      float d1 = ckv[2 * p + 1] - cm;
      float e1 = __builtin_amdgcn_exp2f(fabsf(d1) * 1.44269504f);
      float w1 = (2.0f * adjv[2 * p + 1]) * __builtin_amdgcn_rcpf(1.0f + e1);
      unsigned u0 = __float_as_uint(w0) + 0x8000u;   // round-half-up to bf16
      unsigned u1 = __float_as_uint(w1) + 0x8000u;
      // word = (bf(w1)<<16)|bf(w0): bytes [u0.b2, u0.b3, u1.b2, u1.b3]
      wfu[p] = __builtin_amdgcn_perm(u1, u0, 0x07060302u);
    }
    const bf16x8 wf = __builtin_bit_cast(bf16x8, wfu);

    acc0 = __builtin_amdgcn_mfma_f32_16x16x32_bf16(fa0, wf, acc0, 0, 0, 0);
    acc1 = __builtin_amdgcn_mfma_f32_16x16x32_bf16(fa1, wf, acc1, 0, 0, 0);
  }

  // partials: part[ks][b][c][col]   (D layout: col=l15, row=quad*4+r)
  float* pp = part + ((size_t)(ks * B_DIM + b) * C_DIM) * N_DIM;
#pragma unroll
  for (int r = 0; r < 4; ++r) {
    const int c0 = quad * 4 + r;
    pp[(size_t)c0 * N_DIM + col] = acc0[r];
    pp[(size_t)(c0 + 16) * N_DIM + col] = acc1[r];
  }
}

// Kernel 3: out = relu(para * sum_ks part)
__global__ __launch_bounds__(256) void epilogue_kernel(const float* __restrict__ part,
                                                       const float* __restrict__ para,
                                                       float* __restrict__ out) {
  const int t = blockIdx.x * 256 + threadIdx.x;    // 0 .. 262143 (float4 groups)
  const int m4 = (t & 1023) * 4;
  const int bc = t >> 10;                          // b*32 + c
  const int c = bc & 31;
  const size_t base = (size_t)bc * N_DIM + m4;

  f32x4 s = {0.f, 0.f, 0.f, 0.f};
#pragma unroll
  for (int ks = 0; ks < KSPLIT; ++ks)
    s += *(const f32x4*)(part + (size_t)ks * (B_DIM * C_DIM * N_DIM) + base);

  const f32x4 p = *(const f32x4*)(para + (size_t)c * N_DIM + m4);
  f32x4 o;
#pragma unroll
  for (int i = 0; i < 4; ++i) o[i] = fmaxf(s[i] * p[i], 0.f);
  *(f32x4*)(out + base) = o;
}

extern "C" void kernel_launch(void* const* d_in, const int* in_sizes, int n_in,
                              void* d_out, int out_size, void* d_ws, size_t ws_size,
                              hipStream_t stream) {
  const float* x = (const float*)d_in[0];     // [8,32,64,64]
  const float* para = (const float*)d_in[1];  // [1,32,64,64]
  const float* adj = (const float*)d_in[2];   // [4096,4096]
  float* out = (float*)d_out;

  // ws layout: part (16 MB) | cadj (128 KB) | feab (2 MB)
  float* part = (float*)d_ws;
  float* cadj = (float*)((char*)d_ws + (size_t)KSPLIT * B_DIM * C_DIM * N_DIM * 4);
  ushort* feab = (ushort*)((char*)cadj + (size_t)B_DIM * N_DIM * 4);

  prep_kernel<<<dim3(B_DIM * N_DIM / 256), dim3(256), 0, stream>>>(x, cadj, feab);
  gcn_stage1<<<dim3(N_DIM / 16, KSPLIT), dim3(512), 0, stream>>>(feab, adj, cadj, part);
  epilogue_kernel<<<dim3(B_DIM * C_DIM * N_DIM / 4 / 256), dim3(256), 0, stream>>>(part, para, out);
}

// Round 5
// 189.968 us; speedup vs baseline: 1.0417x; 1.0417x over previous
//
#include <hip/hip_runtime.h>
#include <hip/hip_bf16.h>
#include <math.h>

#define B_DIM 8
#define C_DIM 32
#define N_DIM 4096
#define KSPLIT 2
#define KSL (N_DIM / KSPLIT)   // 2048 K per block

typedef short bf16x8 __attribute__((ext_vector_type(8)));   // 8 bf16 = 4 VGPRs
typedef float f32x4 __attribute__((ext_vector_type(4)));
typedef unsigned int uint4v __attribute__((ext_vector_type(4)));

__device__ __forceinline__ ushort f2bf_rne(float f) {
  unsigned u = __float_as_uint(f);
  u += 0x7FFF + ((u >> 16) & 1);
  return (ushort)(u >> 16);
}

// Kernel 1: cadj[b,n] = mean_c x[b,c,n]; feab[b,c,n] = bf16(x[b,c,n])
__global__ __launch_bounds__(256) void prep_kernel(const float* __restrict__ x,
                                                   float* __restrict__ cadj,
                                                   ushort* __restrict__ feab) {
  int idx = blockIdx.x * 256 + threadIdx.x;   // 0 .. B*N-1
  int b = idx >> 12;
  int n = idx & (N_DIM - 1);
  const float* p = x + (size_t)b * C_DIM * N_DIM + n;
  ushort* q = feab + (size_t)b * C_DIM * N_DIM + n;
  float s = 0.f;
#pragma unroll
  for (int c = 0; c < C_DIM; ++c) {
    float v = p[(size_t)c * N_DIM];
    s += v;
    q[(size_t)c * N_DIM] = f2bf_rne(v);
  }
  cadj[idx] = s * (1.0f / C_DIM);
}

// Kernel 2: block = 8 waves; wave w = batch w; all waves share identical adj
// addresses (L1 reuse). Explicit register double-buffer of next chunk's
// adj/cadj/fea so the 8 strided adj loads overlap weight-gen + MFMA.
// 128-VGPR budget (512,4) leaves room for the pipeline. No LDS, no barriers.
__global__ __launch_bounds__(512, 4) void gcn_stage1(
    const ushort* __restrict__ feab, const float* __restrict__ adj,
    const float* __restrict__ cadj, float* __restrict__ part) {
  const int tid = threadIdx.x;
  const int lane = tid & 63;
  const int b = tid >> 6;           // wave id = batch
  const int quad = lane >> 4;
  const int l15 = lane & 15;
  const int colgrp = blockIdx.x;    // 0..255
  const int ks = blockIdx.y;        // 0..KSPLIT-1
  const int col = colgrp * 16 + l15;
  const int ksbase = ks * KSL;

  const float cm = cadj[b * N_DIM + col];
  const ushort* fb = feab + (size_t)b * C_DIM * N_DIM + ksbase;
  const float* ck = cadj + b * N_DIM + ksbase;

  f32x4 acc0 = {0.f, 0.f, 0.f, 0.f};   // channels 0-15
  f32x4 acc1 = {0.f, 0.f, 0.f, 0.f};   // channels 16-31

  float adjv[2][8];
  float ckv[2][8];
  bf16x8 fa0[2], fa1[2];

#define LOAD_STAGE(ch, s)                                                     \
  {                                                                           \
    const int kb = (ch) * 32 + quad * 8;                                      \
    fa0[s] = *(const bf16x8*)(fb + l15 * N_DIM + kb);                         \
    fa1[s] = *(const bf16x8*)(fb + (16 + l15) * N_DIM + kb);                  \
    *(f32x4*)&ckv[s][0] = *(const f32x4*)(ck + kb);                           \
    *(f32x4*)&ckv[s][4] = *(const f32x4*)(ck + kb + 4);                       \
    _Pragma("unroll")                                                         \
    for (int j = 0; j < 8; ++j)                                               \
      adjv[s][j] = adj[(size_t)(ksbase + kb + j) * N_DIM + col];              \
  }

  LOAD_STAGE(0, 0)

#pragma unroll 2
  for (int ch = 0; ch < KSL / 32; ++ch) {
    const int s = ch & 1;
    if (ch + 1 < KSL / 32) LOAD_STAGE(ch + 1, s ^ 1)

    // w = 2*adj / (1 + exp2(1.4427*|d|));  even in d => symmetrization is identity
    uint4v wfu;
#pragma unroll
    for (int p = 0; p < 4; ++p) {
      float d0 = ckv[s][2 * p] - cm;
      float e0 = __builtin_amdgcn_exp2f(fabsf(d0) * 1.44269504f);
      float w0 = (2.0f * adjv[s][2 * p]) * __builtin_amdgcn_rcpf(1.0f + e0);
      float d1 = ckv[s][2 * p + 1] - cm;
      float e1 = __builtin_amdgcn_exp2f(fabsf(d1) * 1.44269504f);
      float w1 = (2.0f * adjv[s][2 * p + 1]) * __builtin_amdgcn_rcpf(1.0f + e1);
      unsigned u0 = __float_as_uint(w0) + 0x8000u;   // round-half-up to bf16
      unsigned u1 = __float_as_uint(w1) + 0x8000u;
      wfu[p] = __builtin_amdgcn_perm(u1, u0, 0x07060302u);
    }
    const bf16x8 wf = __builtin_bit_cast(bf16x8, wfu);

    acc0 = __builtin_amdgcn_mfma_f32_16x16x32_bf16(fa0[s], wf, acc0, 0, 0, 0);
    acc1 = __builtin_amdgcn_mfma_f32_16x16x32_bf16(fa1[s], wf, acc1, 0, 0, 0);
  }

  // partials: part[ks][b][c][col]   (D layout: col=l15, row=quad*4+r)
  float* pp = part + ((size_t)(ks * B_DIM + b) * C_DIM) * N_DIM;
#pragma unroll
  for (int r = 0; r < 4; ++r) {
    const int c0 = quad * 4 + r;
    pp[(size_t)c0 * N_DIM + col] = acc0[r];
    pp[(size_t)(c0 + 16) * N_DIM + col] = acc1[r];
  }
}

// Kernel 3: out = relu(para * sum_ks part)
__global__ __launch_bounds__(256) void epilogue_kernel(const float* __restrict__ part,
                                                       const float* __restrict__ para,
                                                       float* __restrict__ out) {
  const int t = blockIdx.x * 256 + threadIdx.x;    // float4 groups
  const int m4 = (t & 1023) * 4;
  const int bc = t >> 10;                          // b*32 + c
  const int c = bc & 31;
  const size_t base = (size_t)bc * N_DIM + m4;

  f32x4 s = {0.f, 0.f, 0.f, 0.f};
#pragma unroll
  for (int ks = 0; ks < KSPLIT; ++ks)
    s += *(const f32x4*)(part + (size_t)ks * (B_DIM * C_DIM * N_DIM) + base);

  const f32x4 p = *(const f32x4*)(para + (size_t)c * N_DIM + m4);
  f32x4 o;
#pragma unroll
  for (int i = 0; i < 4; ++i) o[i] = fmaxf(s[i] * p[i], 0.f);
  *(f32x4*)(out + base) = o;
}

extern "C" void kernel_launch(void* const* d_in, const int* in_sizes, int n_in,
                              void* d_out, int out_size, void* d_ws, size_t ws_size,
                              hipStream_t stream) {
  const float* x = (const float*)d_in[0];     // [8,32,64,64]
  const float* para = (const float*)d_in[1];  // [1,32,64,64]
  const float* adj = (const float*)d_in[2];   // [4096,4096]
  float* out = (float*)d_out;

  // ws layout: part (8 MB) | cadj (128 KB) | feab (2 MB)
  float* part = (float*)d_ws;
  float* cadj = (float*)((char*)d_ws + (size_t)KSPLIT * B_DIM * C_DIM * N_DIM * 4);
  ushort* feab = (ushort*)((char*)cadj + (size_t)B_DIM * N_DIM * 4);

  prep_kernel<<<dim3(B_DIM * N_DIM / 256), dim3(256), 0, stream>>>(x, cadj, feab);
  gcn_stage1<<<dim3(N_DIM / 16, KSPLIT), dim3(512), 0, stream>>>(feab, adj, cadj, part);
  epilogue_kernel<<<dim3(B_DIM * C_DIM * N_DIM / 4 / 256), dim3(256), 0, stream>>>(part, para, out);
}

// Round 6
// 156.132 us; speedup vs baseline: 1.2675x; 1.2167x over previous
//
#include <hip/hip_runtime.h>
#include <hip/hip_bf16.h>
#include <math.h>

#define B_DIM 8
#define C_DIM 32
#define N_DIM 4096
#define KSPLIT 8
#define KSL (N_DIM / KSPLIT)   // 512 k per wave
#define NCH (KSL / 32)         // 16 chunks per wave

typedef short bf16x8 __attribute__((ext_vector_type(8)));   // 8 bf16 = 4 VGPRs
typedef float f32x4 __attribute__((ext_vector_type(4)));
typedef unsigned int uint4v __attribute__((ext_vector_type(4)));

__device__ __forceinline__ ushort f2bf_rne(float f) {
  unsigned u = __float_as_uint(f);
  u += 0x7FFF + ((u >> 16) & 1);
  return (ushort)(u >> 16);
}

// Kernel 1: cadj[b,n] = mean_c x[b,c,n]; feabT tiled bf16:
// feabT[((b*128 + n/32)*32 + c)*32 + n%32]  (2KB tile per (b, n/32))
__global__ __launch_bounds__(256) void prep_kernel(const float* __restrict__ x,
                                                   float* __restrict__ cadj,
                                                   ushort* __restrict__ feabT) {
  int idx = blockIdx.x * 256 + threadIdx.x;   // 0 .. B*N-1
  int b = idx >> 12;
  int n = idx & (N_DIM - 1);
  const float* p = x + (size_t)b * C_DIM * N_DIM + n;
  ushort* q = feabT + ((size_t)(b * (N_DIM / 32) + (n >> 5)) * C_DIM) * 32 + (n & 31);
  float s = 0.f;
#pragma unroll
  for (int c = 0; c < C_DIM; ++c) {
    float v = p[(size_t)c * N_DIM];
    s += v;
    q[(size_t)c * 32] = f2bf_rne(v);
  }
  cadj[idx] = s * (1.0f / C_DIM);
}

// Kernel 2: ONE WAVE = 16 cols x 512-k slice x ALL 8 batches.
// adj fragment loaded once per chunk (double-buffered registers), reused by all
// 8 batches -> adj read exactly once from HBM chip-wide. fea frags come from
// contiguous 2KB tiles (coalesced 1KB/instr). Weight-gen VALU (64 w/chunk)
// dominates -> VALU-bound by design. No LDS, no barriers.
__global__ __launch_bounds__(256, 2) void gcn_stage1(
    const ushort* __restrict__ feabT, const float* __restrict__ adj,
    const float* __restrict__ cadj, float* __restrict__ part) {
  const int tid = threadIdx.x;
  const int lane = tid & 63;
  const int wv = tid >> 6;
  const int gw = blockIdx.x * 4 + wv;    // 0..2047
  const int colgrp = gw & 255;
  const int ks = gw >> 8;                // 0..7
  const int quad = lane >> 4;
  const int l15 = lane & 15;
  const int col = colgrp * 16 + l15;
  const int ksbase = ks * KSL;

  float cm[B_DIM];
#pragma unroll
  for (int b = 0; b < B_DIM; ++b) cm[b] = cadj[b * N_DIM + col];

  f32x4 acc[B_DIM][2];
#pragma unroll
  for (int b = 0; b < B_DIM; ++b) {
    acc[b][0] = (f32x4){0.f, 0.f, 0.f, 0.f};
    acc[b][1] = (f32x4){0.f, 0.f, 0.f, 0.f};
  }

  float a2[2][8];   // 2*adj, double-buffered

#define ADJ_STAGE(ch, s)                                                      \
  {                                                                           \
    const int kr = ksbase + (ch) * 32 + quad * 8;                             \
    _Pragma("unroll")                                                         \
    for (int j = 0; j < 8; ++j)                                               \
      a2[s][j] = 2.0f * adj[(size_t)(kr + j) * N_DIM + col];                  \
  }

  ADJ_STAGE(0, 0)

#pragma unroll 2
  for (int ch = 0; ch < NCH; ++ch) {
    const int s = ch & 1;
    if (ch + 1 < NCH) ADJ_STAGE(ch + 1, s ^ 1)

    const int kb = ksbase + ch * 32;     // global k of this chunk
    const int kc = kb >> 5;              // tile index

#pragma unroll
    for (int b = 0; b < B_DIM; ++b) {
      float ckv[8];
      *(f32x4*)&ckv[0] = *(const f32x4*)(cadj + b * N_DIM + kb + quad * 8);
      *(f32x4*)&ckv[4] = *(const f32x4*)(cadj + b * N_DIM + kb + quad * 8 + 4);

      const ushort* tile = feabT + (size_t)(b * (N_DIM / 32) + kc) * (C_DIM * 32);
      const bf16x8 fa0 = *(const bf16x8*)(tile + l15 * 32 + quad * 8);
      const bf16x8 fa1 = *(const bf16x8*)(tile + (16 + l15) * 32 + quad * 8);

      // w = 2*adj / (1 + exp2(1.4427*|d|))  (even in d => symmetrization no-op)
      uint4v wfu;
#pragma unroll
      for (int p = 0; p < 4; ++p) {
        float d0 = ckv[2 * p] - cm[b];
        float e0 = __builtin_amdgcn_exp2f(fabsf(d0) * 1.44269504f);
        float w0 = a2[s][2 * p] * __builtin_amdgcn_rcpf(1.0f + e0);
        float d1 = ckv[2 * p + 1] - cm[b];
        float e1 = __builtin_amdgcn_exp2f(fabsf(d1) * 1.44269504f);
        float w1 = a2[s][2 * p + 1] * __builtin_amdgcn_rcpf(1.0f + e1);
        unsigned u0 = __float_as_uint(w0) + 0x8000u;   // round-half-up to bf16
        unsigned u1 = __float_as_uint(w1) + 0x8000u;
        wfu[p] = __builtin_amdgcn_perm(u1, u0, 0x07060302u);
      }
      const bf16x8 wf = __builtin_bit_cast(bf16x8, wfu);

      acc[b][0] = __builtin_amdgcn_mfma_f32_16x16x32_bf16(fa0, wf, acc[b][0], 0, 0, 0);
      acc[b][1] = __builtin_amdgcn_mfma_f32_16x16x32_bf16(fa1, wf, acc[b][1], 0, 0, 0);
    }
  }

  // partials: part[ks][b][c][col]   (D layout: col=l15, row=quad*4+r)
#pragma unroll
  for (int b = 0; b < B_DIM; ++b) {
    float* pp = part + ((size_t)(ks * B_DIM + b) * C_DIM) * N_DIM;
#pragma unroll
    for (int r = 0; r < 4; ++r) {
      const int c0 = quad * 4 + r;
      pp[(size_t)c0 * N_DIM + col] = acc[b][0][r];
      pp[(size_t)(c0 + 16) * N_DIM + col] = acc[b][1][r];
    }
  }
}

// Kernel 3: out = relu(para * sum_ks part)
__global__ __launch_bounds__(256) void epilogue_kernel(const float* __restrict__ part,
                                                       const float* __restrict__ para,
                                                       float* __restrict__ out) {
  const int t = blockIdx.x * 256 + threadIdx.x;    // float4 groups
  const int m4 = (t & 1023) * 4;
  const int bc = t >> 10;                          // b*32 + c
  const int c = bc & 31;
  const size_t base = (size_t)bc * N_DIM + m4;

  f32x4 s = {0.f, 0.f, 0.f, 0.f};
#pragma unroll
  for (int ks = 0; ks < KSPLIT; ++ks)
    s += *(const f32x4*)(part + (size_t)ks * (B_DIM * C_DIM * N_DIM) + base);

  const f32x4 p = *(const f32x4*)(para + (size_t)c * N_DIM + m4);
  f32x4 o;
#pragma unroll
  for (int i = 0; i < 4; ++i) o[i] = fmaxf(s[i] * p[i], 0.f);
  *(f32x4*)(out + base) = o;
}

extern "C" void kernel_launch(void* const* d_in, const int* in_sizes, int n_in,
                              void* d_out, int out_size, void* d_ws, size_t ws_size,
                              hipStream_t stream) {
  const float* x = (const float*)d_in[0];     // [8,32,64,64]
  const float* para = (const float*)d_in[1];  // [1,32,64,64]
  const float* adj = (const float*)d_in[2];   // [4096,4096]
  float* out = (float*)d_out;

  // ws layout: part (KSPLIT*4MB = 32 MB) | cadj (128 KB) | feabT (2 MB)
  float* part = (float*)d_ws;
  float* cadj = (float*)((char*)d_ws + (size_t)KSPLIT * B_DIM * C_DIM * N_DIM * 4);
  ushort* feabT = (ushort*)((char*)cadj + (size_t)B_DIM * N_DIM * 4);

  prep_kernel<<<dim3(B_DIM * N_DIM / 256), dim3(256), 0, stream>>>(x, cadj, feabT);
  gcn_stage1<<<dim3(256 * KSPLIT / 4), dim3(256), 0, stream>>>(feabT, adj, cadj, part);
  epilogue_kernel<<<dim3(B_DIM * C_DIM * N_DIM / 4 / 256), dim3(256), 0, stream>>>(part, para, out);
}

// Round 7
// 147.086 us; speedup vs baseline: 1.3454x; 1.0615x over previous
//
#include <hip/hip_runtime.h>
#include <hip/hip_bf16.h>
#include <math.h>

#define B_DIM 8
#define C_DIM 32
#define N_DIM 4096
#define KSL 512          // k per wave; 8 waves cover 4096
#define NCH (KSL / 32)   // 16 chunks per wave

typedef short bf16x8 __attribute__((ext_vector_type(8)));   // 8 bf16 = 4 VGPRs
typedef float f32x4 __attribute__((ext_vector_type(4)));
typedef unsigned int uint4v __attribute__((ext_vector_type(4)));

__device__ __forceinline__ ushort f2bf_rne(float f) {
  unsigned u = __float_as_uint(f);
  u += 0x7FFF + ((u >> 16) & 1);
  return (ushort)(u >> 16);
}

// Kernel 1: cadjs[b,n] = mean_c x[b,c,n] * log2(e)  (pre-scaled for exp2);
// feabT tiled bf16: feabT[((b*128 + n/32)*32 + c)*32 + n%32]
__global__ __launch_bounds__(256) void prep_kernel(const float* __restrict__ x,
                                                   float* __restrict__ cadjs,
                                                   ushort* __restrict__ feabT) {
  int idx = blockIdx.x * 256 + threadIdx.x;   // 0 .. B*N-1
  int b = idx >> 12;
  int n = idx & (N_DIM - 1);
  const float* p = x + (size_t)b * C_DIM * N_DIM + n;
  ushort* q = feabT + ((size_t)(b * (N_DIM / 32) + (n >> 5)) * C_DIM) * 32 + (n & 31);
  float s = 0.f;
#pragma unroll
  for (int c = 0; c < C_DIM; ++c) {
    float v = p[(size_t)c * N_DIM];
    s += v;
    q[(size_t)c * 32] = f2bf_rne(v);
  }
  cadjs[idx] = s * (1.44269504f / C_DIM);   // scaled by log2(e): |a-b|*s = |as-bs|
}

// Kernel 2 (fused): block = 8 waves; wave wv = K-slice [wv*512, wv*512+512),
// all 8 batches, 16 cols. adj read once chip-wide (slices disjoint). Batch loop
// software-pipelined depth-2; adj double-buffered and issued mid-chunk so no
// fea vmcnt wait drains it at zero distance. Cross-wave LDS reduce (64 KB,
// 2 passes of 4 batches) + fused para*relu epilogue. No part buffer.
__global__ __launch_bounds__(512, 2) void gcn_fused(
    const ushort* __restrict__ feabT, const float* __restrict__ adj,
    const float* __restrict__ cadjs, const float* __restrict__ para,
    float* __restrict__ out) {
  __shared__ float red[8][2048];   // 64 KB: [wave][b_local*512 + c*16 + col16]

  const int tid = threadIdx.x;
  const int lane = tid & 63;
  const int wv = tid >> 6;          // 0..7 = K-slice
  const int quad = lane >> 4;
  const int l15 = lane & 15;
  const int colgrp = blockIdx.x;    // 0..255
  const int col = colgrp * 16 + l15;
  const int ksbase = wv * KSL;

  float cm[B_DIM];
#pragma unroll
  for (int b = 0; b < B_DIM; ++b) cm[b] = cadjs[b * N_DIM + col];

  f32x4 acc[B_DIM][2];
#pragma unroll
  for (int b = 0; b < B_DIM; ++b) {
    acc[b][0] = (f32x4){0.f, 0.f, 0.f, 0.f};
    acc[b][1] = (f32x4){0.f, 0.f, 0.f, 0.f};
  }

  float a2[2][8];          // 2*adj, double-buffered across chunks
  bf16x8 fa0[2], fa1[2];   // fea fragments, double-buffered across batches
  float ckv[2][8];         // cadjs k-values, double-buffered across batches

#define ADJ_STAGE(ch, s)                                                      \
  {                                                                           \
    const int kr = ksbase + (ch) * 32 + quad * 8;                             \
    _Pragma("unroll")                                                         \
    for (int j = 0; j < 8; ++j)                                               \
      a2[s][j] = 2.0f * adj[(size_t)(kr + j) * N_DIM + col];                  \
  }

#define LOAD_FEA(ch, b_, s)                                                   \
  {                                                                           \
    const int kb2 = ksbase + (ch) * 32;                                       \
    const ushort* tile =                                                      \
        feabT + (size_t)((b_) * (N_DIM / 32) + (kb2 >> 5)) * (C_DIM * 32);    \
    fa0[s] = *(const bf16x8*)(tile + l15 * 32 + quad * 8);                    \
    fa1[s] = *(const bf16x8*)(tile + (16 + l15) * 32 + quad * 8);             \
    *(f32x4*)&ckv[s][0] = *(const f32x4*)(cadjs + (b_)*N_DIM + kb2 + quad * 8); \
    *(f32x4*)&ckv[s][4] = *(const f32x4*)(cadjs + (b_)*N_DIM + kb2 + quad * 8 + 4); \
  }

  ADJ_STAGE(0, 0)
  LOAD_FEA(0, 0, 0)

#pragma unroll 2
  for (int ch = 0; ch < NCH; ++ch) {
    const int s = ch & 1;

#pragma unroll
    for (int b = 0; b < B_DIM; ++b) {
      const int sb = b & 1;
      // prefetch next batch (or batch 0 of next chunk)
      if (b < B_DIM - 1) {
        LOAD_FEA(ch, b + 1, sb ^ 1)
      } else if (ch + 1 < NCH) {
        LOAD_FEA(ch + 1, 0, 0)
      }
      // adj prefetch issued mid-chunk: nearest later fea-wait is ~1 batch away
      if (b == 1 && ch + 1 < NCH) ADJ_STAGE(ch + 1, s ^ 1)

      // w = 2*adj / (1 + exp2(|ck' - cm'|)), inputs pre-scaled by log2(e)
      uint4v wfu;
#pragma unroll
      for (int p = 0; p < 4; ++p) {
        float d0 = ckv[sb][2 * p] - cm[b];
        float e0 = __builtin_amdgcn_exp2f(fabsf(d0));
        float w0 = a2[s][2 * p] * __builtin_amdgcn_rcpf(1.0f + e0);
        float d1 = ckv[sb][2 * p + 1] - cm[b];
        float e1 = __builtin_amdgcn_exp2f(fabsf(d1));
        float w1 = a2[s][2 * p + 1] * __builtin_amdgcn_rcpf(1.0f + e1);
        // truncating bf16x2 pack: bytes [w0.b2, w0.b3, w1.b2, w1.b3]
        wfu[p] = __builtin_amdgcn_perm(__float_as_uint(w1), __float_as_uint(w0),
                                       0x07060302u);
      }
      const bf16x8 wf = __builtin_bit_cast(bf16x8, wfu);

      acc[b][0] = __builtin_amdgcn_mfma_f32_16x16x32_bf16(fa0[sb], wf, acc[b][0], 0, 0, 0);
      acc[b][1] = __builtin_amdgcn_mfma_f32_16x16x32_bf16(fa1[sb], wf, acc[b][1], 0, 0, 0);
    }
  }

  // para value for this thread's (c, col16) slot in the reduce phase
  const float pv = para[(size_t)(tid >> 4) * N_DIM + colgrp * 16 + (tid & 15)];

  // cross-wave reduction + epilogue, 2 passes of 4 batches (LDS = 64 KB)
#pragma unroll
  for (int pass = 0; pass < 2; ++pass) {
    if (pass) __syncthreads();   // pass-0 reads done before overwrite
#pragma unroll
    for (int bl = 0; bl < 4; ++bl) {
      const int b = pass * 4 + bl;
#pragma unroll
      for (int h = 0; h < 2; ++h)
#pragma unroll
        for (int r = 0; r < 4; ++r)
          red[wv][bl * 512 + (h * 16 + quad * 4 + r) * 16 + l15] = acc[b][h][r];
    }
    __syncthreads();
#pragma unroll
    for (int q = 0; q < 4; ++q) {
      float ssum = 0.f;
#pragma unroll
      for (int w = 0; w < 8; ++w) ssum += red[w][q * 512 + tid];
      const int b = pass * 4 + q;
      const int c = tid >> 4;
      const int ocol = colgrp * 16 + (tid & 15);
      out[((size_t)(b * C_DIM + c)) * N_DIM + ocol] = fmaxf(ssum * pv, 0.f);
    }
  }
}

extern "C" void kernel_launch(void* const* d_in, const int* in_sizes, int n_in,
                              void* d_out, int out_size, void* d_ws, size_t ws_size,
                              hipStream_t stream) {
  const float* x = (const float*)d_in[0];     // [8,32,64,64]
  const float* para = (const float*)d_in[1];  // [1,32,64,64]
  const float* adj = (const float*)d_in[2];   // [4096,4096]
  float* out = (float*)d_out;

  // ws: cadjs (128 KB) | feabT (2 MB)  -- total 2.25 MB (poison cost matters!)
  float* cadjs = (float*)d_ws;
  ushort* feabT = (ushort*)((char*)d_ws + (size_t)B_DIM * N_DIM * 4);

  prep_kernel<<<dim3(B_DIM * N_DIM / 256), dim3(256), 0, stream>>>(x, cadjs, feabT);
  gcn_fused<<<dim3(N_DIM / 16), dim3(512), 0, stream>>>(feabT, adj, cadjs, para, out);
}